// Round 8
// baseline (4879.535 us; speedup 1.0000x reference)
//
#include <hip/hip_runtime.h>

// Problem constants
#define TSTEPS 1024
#define HDIM   1024
#define INDIM  512
#define NGATE  4096     // 4*HDIM

// Fused-scan grid: 192 WGs x 1024 threads (proven-launchable coop envelope).
// L1 (wg<64): 16 units/WG, wave q owns unit u0+q, all 4 gates.
// L23: 8 units/WG, wave q owns unit u0+(q>>1), gate pair q&1, serving BOTH
//      layer 2 and layer 3 (shared weights).
#define NWG_L1  64
#define NWG_L23 128
#define NWG_TOT 192
#define POISON  0xAAAAAAAAu
#define SPIN_MAX (1 << 20)   // deadlock valve: fail loud, never hang

// ---------------------------------------------------------------------------
// Agent-scope RELAXED ops (global sc0 sc1 -> coherent LLC, no cache maint).
// Dataflow sync: H1/H2/H3 pre-poisoned 0xAA; consumers poll the data itself.
// R7 post-mortem: VGPR_Count=64 proved the compiler sank the 64-float weight
// arrays back into the t-loop (legal under __restrict__: no aliasing stores
// -> reload allowed) => ~48 MB/step of L2 weight re-fetch ≈ 1.4-2us/step.
// Fix: fused_scan takes NON-restrict pointers, so H-stores may alias the
// weight matrices and reloading across them is ILLEGAL -> weights must stay
// VGPR-resident. Verify via VGPR_Count ~110-128.
// ---------------------------------------------------------------------------
__device__ __forceinline__ float agent_loadf(const float* p) {
    return __hip_atomic_load(const_cast<float*>(p), __ATOMIC_RELAXED,
                             __HIP_MEMORY_SCOPE_AGENT);
}
__device__ __forceinline__ void agent_storef(float* p, float v) {
    __hip_atomic_store(p, v, __ATOMIC_RELAXED, __HIP_MEMORY_SCOPE_AGENT);
}
// Wave-cooperative poll: each lane owns one dword; loop until no lane's
// dword is the poison pattern. The poll IS the data load.
__device__ __forceinline__ float poll_row(const float* p) {
    float v = 0.f;
    for (int it = 0; it < SPIN_MAX; ++it) {
        v = agent_loadf(p);
        if (__ballot(__float_as_uint(v) == POISON) == 0ULL) break;
        __builtin_amdgcn_s_sleep(1);
    }
    return v;
}
__device__ __forceinline__ float wave_sum64(float v) {
#pragma unroll
    for (int d = 1; d < 64; d <<= 1) v += __shfl_xor(v, d, 64);
    return v;
}
__device__ __forceinline__ float sigm(float x) { return 1.f / (1.f + __expf(-x)); }

// ---------------------------------------------------------------------------
// GEMM for layer-1 input gates: G[t][n] = concat(x,time)[t] . Wih1[n] + b.
// ---------------------------------------------------------------------------
#define BM 64
#define BN 64
#define BK 32

__global__ __launch_bounds__(256) void gemm_tn(
    const float* __restrict__ B,
    const float* __restrict__ bias1,
    const float* __restrict__ bias2,
    float* __restrict__ C,
    int M, int N, int K,
    const float* __restrict__ x,
    const float* __restrict__ timev)
{
    __shared__ float As[BK][BM + 4];
    __shared__ float Bs[BK][BN + 4];

    const int tid = threadIdx.x;
    const int mblocks = M / BM;
    const int bm = blockIdx.x % mblocks;
    const int bn = blockIdx.x / mblocks;
    const int t0 = bm * BM;
    const int n0 = bn * BN;

    const int tx = tid & 15;
    const int ty = tid >> 4;

    float acc[4][4] = {{0.f}};

    for (int kc = 0; kc < K; kc += BK) {
#pragma unroll
        for (int i = 0; i < 8; i++) {
            int idx = tid + i * 256;
            int r = idx >> 5;
            int c = idx & 31;
            int col = kc + c;
            int trow = t0 + r;
            float av = (col < INDIM) ? x[(size_t)trow * INDIM + col]
                                     : ((col == INDIM) ? timev[trow] : 0.f);
            As[c][r] = av;
            int nrow = n0 + r;
            Bs[c][r] = (col < K) ? B[(size_t)nrow * K + col] : 0.f;
        }
        __syncthreads();

#pragma unroll
        for (int kk = 0; kk < BK; kk++) {
            float a[4], b[4];
#pragma unroll
            for (int i = 0; i < 4; i++) a[i] = As[kk][ty * 4 + i];
#pragma unroll
            for (int j = 0; j < 4; j++) b[j] = Bs[kk][tx * 4 + j];
#pragma unroll
            for (int i = 0; i < 4; i++)
#pragma unroll
                for (int j = 0; j < 4; j++)
                    acc[i][j] = fmaf(a[i], b[j], acc[i][j]);
        }
        __syncthreads();
    }

#pragma unroll
    for (int i = 0; i < 4; i++) {
        int trow = t0 + ty * 4 + i;
#pragma unroll
        for (int j = 0; j < 4; j++) {
            int n = n0 + tx * 4 + j;
            C[(size_t)trow * N + n] = acc[i][j] + bias1[n] + bias2[n];
        }
    }
}

// ---------------------------------------------------------------------------
// Fused dataflow 3-layer scan. No barriers, no flags. NOTE: pointers are
// deliberately NOT __restrict__ (see header comment — forces weight
// VGPR-residency).
// ---------------------------------------------------------------------------
__global__ __launch_bounds__(1024, 4) void fused_scan(
    const float* Whh1,
    const float* G1,
    const float* Wih2,
    const float* Whh2,
    const float* bih2,
    const float* bhh2,
    const float* h0_1, const float* c0_1,
    const float* h0_2, const float* c0_2,
    const float* h0_3, const float* c0_3,
    float* H1, float* H2, float* H3)
{
    __shared__ float hs1[HDIM];
    __shared__ float hs2[HDIM];
    __shared__ float hs3[HDIM];
    __shared__ float gbuf[16][4];  // L1: [unit 0..15][gate]; L23: 0-7 L2, 8-15 L3

    const int tid = threadIdx.x;
    const int wg  = blockIdx.x;
    const int q   = tid >> 6;      // wave 0..15
    const int s   = tid & 63;

    if (wg < NWG_L1) {
        // ------- Layer 1: WG owns 16 units, wave q owns unit u0+q -------
        const int u0 = wg << 4;
        const int u  = u0 + q;
        float2 w[4][8];
#pragma unroll
        for (int g = 0; g < 4; ++g) {
            const float* row = Whh1 + (size_t)((g << 10) + u) * HDIM + 2 * s;
#pragma unroll
            for (int m = 0; m < 8; ++m)
                w[g][m] = *(const float2*)(row + 128 * m);
        }
        float c1 = (tid < 16) ? c0_1[u0 + tid] : 0.f;
        asm volatile("" ::: "memory");   // pin: weights loaded before loop

        for (int t = 0; t < TSTEPS; ++t) {
            float Gv0 = 0.f, Gv1 = 0.f, Gv2 = 0.f, Gv3 = 0.f;
            if (tid < 16) {   // prefetch gate inputs (normal cached loads)
                const float* gptr = G1 + (size_t)t * NGATE + u0 + tid;
                Gv0 = gptr[0];
                Gv1 = gptr[1024];
                Gv2 = gptr[2048];
                Gv3 = gptr[3072];
            }
            // stage h1[t-1]: poll the data itself
            hs1[tid] = (t == 0) ? h0_1[tid]
                               : poll_row(H1 + (size_t)(t - 1) * HDIM + tid);
            __syncthreads();                                   // A: staged

            float2 a0 = make_float2(0.f, 0.f), a1 = a0, a2 = a0, a3 = a0;
#pragma unroll
            for (int m = 0; m < 8; ++m) {
                float2 hv = *(const float2*)&hs1[2 * s + 128 * m];
                a0.x = fmaf(w[0][m].x, hv.x, a0.x);
                a0.y = fmaf(w[0][m].y, hv.y, a0.y);
                a1.x = fmaf(w[1][m].x, hv.x, a1.x);
                a1.y = fmaf(w[1][m].y, hv.y, a1.y);
                a2.x = fmaf(w[2][m].x, hv.x, a2.x);
                a2.y = fmaf(w[2][m].y, hv.y, a2.y);
                a3.x = fmaf(w[3][m].x, hv.x, a3.x);
                a3.y = fmaf(w[3][m].y, hv.y, a3.y);
            }
            float s0 = wave_sum64(a0.x + a0.y);
            float s1 = wave_sum64(a1.x + a1.y);
            float s2 = wave_sum64(a2.x + a2.y);
            float s3 = wave_sum64(a3.x + a3.y);
            if (s == 0) {
                gbuf[q][0] = s0;
                gbuf[q][1] = s1;
                gbuf[q][2] = s2;
                gbuf[q][3] = s3;
            }
            __syncthreads();                                   // B: sums ready

            if (tid < 16) {
                float gi = gbuf[tid][0] + Gv0;
                float gf = gbuf[tid][1] + Gv1;
                float gg = gbuf[tid][2] + Gv2;
                float go = gbuf[tid][3] + Gv3;
                float i_ = sigm(gi), f_ = sigm(gf), g_ = tanhf(gg), o_ = sigm(go);
                c1 = f_ * c1 + i_ * g_;
                float hn = o_ * tanhf(c1);
                agent_storef(H1 + (size_t)t * HDIM + u0 + tid, hn);
            }
            // no drain, no flag: the stored dwords ARE the signal
        }
    } else {
        // ---- Layers 2 & 3 (shared weights): WG owns 8 units ----
        const int ul = q >> 1;     // unit-local 0..7
        const int gp = q & 1;      // 0 -> gates (i,f), 1 -> gates (g,o)
        const int u0 = (wg - NWG_L1) << 3;
        const int u  = u0 + ul;
        float2 wi[2][8], wh[2][8];
#pragma unroll
        for (int j = 0; j < 2; ++j) {
            const float* ri = Wih2 + (size_t)(((2 * gp + j) << 10) + u) * HDIM + 2 * s;
            const float* rh = Whh2 + (size_t)(((2 * gp + j) << 10) + u) * HDIM + 2 * s;
#pragma unroll
            for (int m = 0; m < 8; ++m) {
                wi[j][m] = *(const float2*)(ri + 128 * m);
                wh[j][m] = *(const float2*)(rh + 128 * m);
            }
        }
        float bias0 = 0.f, bias1v = 0.f, bias2v = 0.f, bias3 = 0.f, cst = 0.f;
        if (tid < 16) {
            int uu = u0 + (tid & 7);
            bias0  = bih2[uu]        + bhh2[uu];
            bias1v = bih2[1024 + uu] + bhh2[1024 + uu];
            bias2v = bih2[2048 + uu] + bhh2[2048 + uu];
            bias3  = bih2[3072 + uu] + bhh2[3072 + uu];
            cst = (tid < 8) ? c0_2[u0 + tid] : c0_3[u0 + tid - 8];
        }
        asm volatile("" ::: "memory");   // pin: weights loaded before loop

        // iteration t: layer2 tick t (needs h1[t], h2[t-1]) and
        //              layer3 tick t-1 (needs h2[t-1], h3[t-2])
        for (int t = 0; t <= TSTEPS; ++t) {
            const bool do2 = (t < TSTEPS);
            const bool do3 = (t >= 1);

            if (do2)
                hs1[tid] = poll_row(H1 + (size_t)t * HDIM + tid);
            hs2[tid] = (t == 0) ? h0_2[tid]
                                : poll_row(H2 + (size_t)(t - 1) * HDIM + tid);
            if (do3)
                hs3[tid] = (t == 1) ? h0_3[tid]
                                    : poll_row(H3 + (size_t)(t - 2) * HDIM + tid);
            __syncthreads();                                   // A: staged

            // unconditional dots; inactive-edge garbage discarded at update
            float2 p20 = make_float2(0.f, 0.f), p21 = p20, p30 = p20, p31 = p20;
#pragma unroll
            for (int m = 0; m < 8; ++m) {
                float2 h1v = *(const float2*)&hs1[2 * s + 128 * m];
                float2 h2v = *(const float2*)&hs2[2 * s + 128 * m];
                float2 h3v = *(const float2*)&hs3[2 * s + 128 * m];
                p20.x = fmaf(wi[0][m].x, h1v.x, p20.x);
                p20.y = fmaf(wi[0][m].y, h1v.y, p20.y);
                p21.x = fmaf(wi[1][m].x, h1v.x, p21.x);
                p21.y = fmaf(wi[1][m].y, h1v.y, p21.y);
                p20.x = fmaf(wh[0][m].x, h2v.x, p20.x);
                p20.y = fmaf(wh[0][m].y, h2v.y, p20.y);
                p21.x = fmaf(wh[1][m].x, h2v.x, p21.x);
                p21.y = fmaf(wh[1][m].y, h2v.y, p21.y);
                p30.x = fmaf(wi[0][m].x, h2v.x, p30.x);
                p30.y = fmaf(wi[0][m].y, h2v.y, p30.y);
                p31.x = fmaf(wi[1][m].x, h2v.x, p31.x);
                p31.y = fmaf(wi[1][m].y, h2v.y, p31.y);
                p30.x = fmaf(wh[0][m].x, h3v.x, p30.x);
                p30.y = fmaf(wh[0][m].y, h3v.y, p30.y);
                p31.x = fmaf(wh[1][m].x, h3v.x, p31.x);
                p31.y = fmaf(wh[1][m].y, h3v.y, p31.y);
            }
            float s20 = wave_sum64(p20.x + p20.y);
            float s21 = wave_sum64(p21.x + p21.y);
            float s30 = wave_sum64(p30.x + p30.y);
            float s31 = wave_sum64(p31.x + p31.y);
            if (s == 0) {
                gbuf[ul][2 * gp]          = s20;
                gbuf[ul][2 * gp + 1]      = s21;
                gbuf[8 + ul][2 * gp]      = s30;
                gbuf[8 + ul][2 * gp + 1]  = s31;
            }
            __syncthreads();                                   // B: sums ready

            if (tid < 16) {
                const bool act = (tid < 8) ? do2 : do3;
                if (act) {
                    float gi = gbuf[tid][0] + bias0;
                    float gf = gbuf[tid][1] + bias1v;
                    float gg = gbuf[tid][2] + bias2v;
                    float go = gbuf[tid][3] + bias3;
                    float i_ = sigm(gi), f_ = sigm(gf), g_ = tanhf(gg), o_ = sigm(go);
                    cst = f_ * cst + i_ * g_;
                    float hn = o_ * tanhf(cst);
                    float* dst = (tid < 8)
                        ? (H2 + (size_t)t * HDIM + u0 + tid)
                        : (H3 + (size_t)(t - 1) * HDIM + u0 + (tid - 8));
                    agent_storef(dst, hn);
                }
            }
        }
    }
}

// ---------------------------------------------------------------------------
// Attention
// ---------------------------------------------------------------------------
__global__ __launch_bounds__(256) void attn_dot(
    const float* __restrict__ H3, float* __restrict__ attn)
{
    const int t = blockIdx.x * 4 + (threadIdx.x >> 6);
    const int lane = threadIdx.x & 63;
    const float* hrow = H3 + (size_t)t * HDIM;
    const float* hf = H3 + (size_t)(TSTEPS - 1) * HDIM;
    float p = 0.f;
    for (int j = lane; j < HDIM; j += 64) p = fmaf(hrow[j], hf[j], p);
#pragma unroll
    for (int d = 32; d; d >>= 1) p += __shfl_down(p, d, 64);
    if (lane == 0) attn[t] = p;
}

__global__ __launch_bounds__(64) void softmax_1024(float* attn)
{
    const int lane = threadIdx.x;
    float vals[16];
    float m = -1e30f;
#pragma unroll
    for (int i = 0; i < 16; i++) {
        vals[i] = attn[lane + i * 64];
        m = fmaxf(m, vals[i]);
    }
#pragma unroll
    for (int d = 32; d; d >>= 1) m = fmaxf(m, __shfl_xor(m, d, 64));
    float s = 0.f;
#pragma unroll
    for (int i = 0; i < 16; i++) {
        vals[i] = expf(vals[i] - m);
        s += vals[i];
    }
#pragma unroll
    for (int d = 32; d; d >>= 1) s += __shfl_xor(s, d, 64);
    float inv = 1.f / s;
#pragma unroll
    for (int i = 0; i < 16; i++) attn[lane + i * 64] = vals[i] * inv;
}

__global__ __launch_bounds__(256) void context_kernel(
    const float* __restrict__ H3, const float* __restrict__ w,
    float* __restrict__ out)
{
    const int u = blockIdx.x * 4 + (threadIdx.x >> 6);
    const int lane = threadIdx.x & 63;
    float p = 0.f;
    for (int t = lane; t < TSTEPS; t += 64)
        p = fmaf(H3[(size_t)t * HDIM + u], w[t], p);
#pragma unroll
    for (int d = 32; d; d >>= 1) p += __shfl_down(p, d, 64);
    if (lane == 0) out[u] = p;
}

// ---------------------------------------------------------------------------
// Launch
// ---------------------------------------------------------------------------
extern "C" void kernel_launch(void* const* d_in, const int* in_sizes, int n_in,
                              void* d_out, int out_size, void* d_ws, size_t ws_size,
                              hipStream_t stream)
{
    const float* x     = (const float*)d_in[0];
    const float* timev = (const float*)d_in[1];
    const float* h0_1  = (const float*)d_in[2];
    const float* c0_1  = (const float*)d_in[3];
    const float* h0_2  = (const float*)d_in[4];
    const float* c0_2  = (const float*)d_in[5];
    const float* h0_3  = (const float*)d_in[6];
    const float* c0_3  = (const float*)d_in[7];
    const float* Wih1  = (const float*)d_in[8];
    const float* Whh1  = (const float*)d_in[9];
    const float* bih1  = (const float*)d_in[10];
    const float* bhh1  = (const float*)d_in[11];
    const float* Wih2  = (const float*)d_in[12];
    const float* Whh2  = (const float*)d_in[13];
    const float* bih2  = (const float*)d_in[14];
    const float* bhh2  = (const float*)d_in[15];

    float* ws   = (float*)d_ws;
    float* G    = ws;                          // 1024*4096
    float* H1   = G + (size_t)TSTEPS * NGATE;
    float* H2   = H1 + (size_t)TSTEPS * HDIM;
    float* H3   = H2 + (size_t)TSTEPS * HDIM;
    float* attn = H3 + (size_t)TSTEPS * HDIM;
    float* out  = (float*)d_out;

    // Poison H1..H3 (contiguous): the data-poll protocol depends on it.
    hipMemsetAsync(H1, 0xAA, (size_t)3 * TSTEPS * HDIM * sizeof(float), stream);

    // Layer-1 input gates: G = concat(x,time) @ Wih1^T + bih1 + bhh1
    gemm_tn<<<dim3(1024), dim3(256), 0, stream>>>(Wih1, bih1, bhh1, G,
                                                  TSTEPS, NGATE, INDIM + 1, x, timev);

    {
        const float* a0 = Whh1;  const float* a1 = G;
        const float* a2 = Wih2;  const float* a3 = Whh2;
        const float* a4 = bih2;  const float* a5 = bhh2;
        const float* a6 = h0_1;  const float* a7 = c0_1;
        const float* a8 = h0_2;  const float* a9 = c0_2;
        const float* a10 = h0_3; const float* a11 = c0_3;
        float* a12 = H1; float* a13 = H2; float* a14 = H3;
        void* args[] = {&a0,&a1,&a2,&a3,&a4,&a5,&a6,&a7,&a8,&a9,&a10,&a11,
                        &a12,&a13,&a14};
        hipLaunchCooperativeKernel((void*)fused_scan, dim3(NWG_TOT), dim3(1024),
                                   args, 0, stream);
    }

    // Attention
    attn_dot<<<dim3(256), dim3(256), 0, stream>>>(H3, attn);
    softmax_1024<<<dim3(1), dim3(64), 0, stream>>>(attn);
    context_kernel<<<dim3(256), dim3(256), 0, stream>>>(H3, attn, out);
}